// Round 1
// baseline (90.392 us; speedup 1.0000x reference)
//
#include <hip/hip_runtime.h>
#include <math.h>

#define C 64
#define IN_DIM 148
#define ODIM 9      // outputs per edge
#define PDIM 18     // src(9) + dst(9) projections per node
#define NPT 4       // nodes per thread in node kernel

__device__ __forceinline__ float tanh_fast(float x) {
    // tanh(x) = 1 - 2/(e^{2x}+1); saturates correctly at +/-inf
    float e = __expf(2.0f * x);
    return 1.0f - 2.0f / (e + 1.0f);
}

// ---------------- node projection kernel ----------------
// proj layout: sp[n][pad] then dp[n][pad] (two arrays in ws), pad=16 floats (64B rows)
__global__ __launch_bounds__(256) void node_proj_kernel(
    const float* __restrict__ x, const int* __restrict__ node_types,
    const float* __restrict__ W, float* __restrict__ sp, float* __restrict__ dp,
    int N, int pad)
{
    __shared__ float Wl[PDIM * C];      // row r<9: W[r][c]; row r>=9: W[r-9][64+c]
    __shared__ float ntab[2][ODIM][4];  // [0]=src-type consts, [1]=dst-type consts

    for (int i = threadIdx.x; i < PDIM * C; i += 256) {
        int r = i >> 6, c = i & 63;
        int o = (r < ODIM) ? r : r - ODIM;
        int col = (r < ODIM) ? c : (C + c);
        Wl[i] = W[o * IN_DIM + col];
    }
    for (int i = threadIdx.x; i < 2 * ODIM * 4; i += 256) {
        int t = i & 3;
        int o = (i >> 2) % ODIM;
        int sd = (i >> 2) / ODIM;
        ntab[sd][o][t] = W[o * IN_DIM + 128 + sd * 4 + t];
    }
    __syncthreads();

    int tid = blockIdx.x * 256 + threadIdx.x;
    int n0 = tid * NPT;
    if (n0 >= N) return;

    float acc[NPT][PDIM];
#pragma unroll
    for (int k = 0; k < NPT; ++k)
#pragma unroll
        for (int o = 0; o < PDIM; ++o) acc[k][o] = 0.0f;

    size_t nb[NPT];
#pragma unroll
    for (int k = 0; k < NPT; ++k) {
        int n = n0 + k;
        if (n > N - 1) n = N - 1;       // clamp; duplicate work, store guarded
        nb[k] = (size_t)n * C;
    }

    for (int c4 = 0; c4 < C / 4; ++c4) {
        float4 xv[NPT];
#pragma unroll
        for (int k = 0; k < NPT; ++k)
            xv[k] = *(const float4*)(x + nb[k] + c4 * 4);
#pragma unroll
        for (int j = 0; j < 4; ++j) {
            int c = c4 * 4 + j;
#pragma unroll
            for (int o = 0; o < PDIM; ++o) {
                float w = Wl[o * C + c];
#pragma unroll
                for (int k = 0; k < NPT; ++k) {
                    float xs = (j == 0) ? xv[k].x : (j == 1) ? xv[k].y
                             : (j == 2) ? xv[k].z : xv[k].w;
                    acc[k][o] = fmaf(xs, w, acc[k][o]);
                }
            }
        }
    }

#pragma unroll
    for (int k = 0; k < NPT; ++k) {
        int n = n0 + k;
        if (n >= N) break;
        int t = node_types[n];
        float* sprow = sp + (size_t)n * pad;
        float* dprow = dp + (size_t)n * pad;
#pragma unroll
        for (int o = 0; o < ODIM; ++o) {
            sprow[o] = acc[k][o] + ntab[0][o][t];
            dprow[o] = acc[k][ODIM + o] + ntab[1][o][t];
        }
    }
}

// ---------------- edge kernel: one thread per output element ----------------
__global__ __launch_bounds__(256) void edge_kernel(
    const int* __restrict__ ei, const int* __restrict__ etypes,
    const float* __restrict__ sp, const float* __restrict__ dp,
    const float* __restrict__ W, float* __restrict__ out,
    int E, int pad)
{
    __shared__ float etab[12 * ODIM];   // etab[t*9+o] = W[o][136+t]
    for (int i = threadIdx.x; i < 12 * ODIM; i += 256) {
        int t = i / ODIM, o = i - t * ODIM;
        etab[i] = W[o * IN_DIM + 136 + t];
    }
    __syncthreads();

    int i = blockIdx.x * 256 + threadIdx.x;
    int total = E * ODIM;               // 14.4M fits int32
    if (i >= total) return;

    unsigned e = (unsigned)i / 9u;      // magic-mul division
    int o = i - (int)e * 9;

    int s  = ei[e];
    int d  = ei[(size_t)E + e];
    int et = etypes[e];

    float v = sp[(size_t)s * pad + o] + dp[(size_t)d * pad + o] + etab[et * ODIM + o];
    out[i] = tanh_fast(v);
}

extern "C" void kernel_launch(void* const* d_in, const int* in_sizes, int n_in,
                              void* d_out, int out_size, void* d_ws, size_t ws_size,
                              hipStream_t stream) {
    const float* x      = (const float*)d_in[0];
    const int*   ei     = (const int*)d_in[1];
    const int*   etypes = (const int*)d_in[2];
    const int*   ntypes = (const int*)d_in[3];
    const float* W      = (const float*)d_in[4];
    float* out = (float*)d_out;

    int N = in_sizes[0] / C;    // 100000
    int E = in_sizes[2];        // 1600000

    int pad = 16;               // 64B-aligned proj rows
    if (ws_size < (size_t)N * pad * 2 * sizeof(float)) pad = ODIM; // fallback
    float* sp = (float*)d_ws;
    float* dp = sp + (size_t)N * pad;

    int nthreads = (N + NPT - 1) / NPT;
    int nblocks  = (nthreads + 255) / 256;
    node_proj_kernel<<<nblocks, 256, 0, stream>>>(x, ntypes, W, sp, dp, N, pad);

    long total = (long)E * ODIM;
    int eblocks = (int)((total + 255) / 256);
    edge_kernel<<<eblocks, 256, 0, stream>>>(ei, etypes, sp, dp, W, out, E, pad);
}

// Round 2
// 75.823 us; speedup vs baseline: 1.1921x; 1.1921x over previous
//
#include <hip/hip_runtime.h>
#include <hip/hip_fp16.h>
#include <math.h>

#define C 64
#define IN_DIM 148
#define ODIM 9      // outputs per edge
#define PDIM 18     // src(9) + dst(9) projections per node
#define PPAD 16     // halfs per proj row (32 B, cache-friendly)

typedef _Float16 half_t;

__device__ __forceinline__ float tanh_fast(float x) {
    // tanh(x) = 1 - 2/(e^{2x}+1); saturates correctly at +/-inf
    float e = __expf(2.0f * x);
    return 1.0f - 2.0f / (e + 1.0f);
}

// ---------------- node projection kernel: 1 thread per node ----------------
__global__ __launch_bounds__(256) void node_proj_kernel(
    const float* __restrict__ x, const int* __restrict__ node_types,
    const float* __restrict__ W, half_t* __restrict__ sp, half_t* __restrict__ dp,
    int N)
{
    __shared__ float Wl[PDIM][C];       // r<9: W[r][c]; r>=9: W[r-9][64+c]
    __shared__ float ntab[2][ODIM][4];  // [0]=src-type consts, [1]=dst-type consts

    for (int i = threadIdx.x; i < PDIM * C; i += 256) {
        int r = i >> 6, c = i & 63;
        int o = (r < ODIM) ? r : r - ODIM;
        int col = (r < ODIM) ? c : (C + c);
        Wl[r][c] = W[o * IN_DIM + col];
    }
    for (int i = threadIdx.x; i < 2 * ODIM * 4; i += 256) {
        int t = i & 3;
        int o = (i >> 2) % ODIM;
        int sd = (i >> 2) / ODIM;
        ntab[sd][o][t] = W[o * IN_DIM + 128 + sd * 4 + t];
    }
    __syncthreads();

    int n = blockIdx.x * 256 + threadIdx.x;
    if (n >= N) return;

    // whole x-row in registers (16 float4 = 64 VGPR)
    float4 xv[16];
    const float4* xr = (const float4*)(x + (size_t)n * C);
#pragma unroll
    for (int q = 0; q < 16; ++q) xv[q] = xr[q];

    float acc[PDIM];
#pragma unroll
    for (int o = 0; o < PDIM; ++o) acc[o] = 0.0f;

#pragma unroll
    for (int q = 0; q < 16; ++q) {
#pragma unroll
        for (int o = 0; o < PDIM; ++o) {
            float4 w = *(const float4*)&Wl[o][q * 4];   // ds_read_b128, broadcast
            acc[o] = fmaf(xv[q].x, w.x, acc[o]);
            acc[o] = fmaf(xv[q].y, w.y, acc[o]);
            acc[o] = fmaf(xv[q].z, w.z, acc[o]);
            acc[o] = fmaf(xv[q].w, w.w, acc[o]);
        }
    }

    int t = node_types[n];
    half_t* sr = sp + (size_t)n * PPAD;
    half_t* dr = dp + (size_t)n * PPAD;
#pragma unroll
    for (int o = 0; o < ODIM; ++o) {
        sr[o] = (half_t)(acc[o] + ntab[0][o][t]);
        dr[o] = (half_t)(acc[ODIM + o] + ntab[1][o][t]);
    }
}

// ---------------- edge kernel: one thread per output element ----------------
__global__ __launch_bounds__(256) void edge_kernel(
    const int* __restrict__ ei, const int* __restrict__ etypes,
    const half_t* __restrict__ sp, const half_t* __restrict__ dp,
    const float* __restrict__ W, float* __restrict__ out,
    int E)
{
    __shared__ float etab[12 * ODIM];   // etab[t*9+o] = W[o][136+t]
    for (int i = threadIdx.x; i < 12 * ODIM; i += 256) {
        int t = i / ODIM, o = i - t * ODIM;
        etab[i] = W[o * IN_DIM + 136 + t];
    }
    __syncthreads();

    int i = blockIdx.x * 256 + threadIdx.x;
    int total = E * ODIM;               // 14.4M fits int32
    if (i >= total) return;

    unsigned e = (unsigned)i / 9u;      // magic-mul division
    int o = i - (int)e * 9;

    int s  = ei[e];
    int d  = ei[(size_t)E + e];
    int et = etypes[e];

    float v = (float)sp[(size_t)s * PPAD + o]
            + (float)dp[(size_t)d * PPAD + o]
            + etab[et * ODIM + o];
    out[i] = tanh_fast(v);
}

extern "C" void kernel_launch(void* const* d_in, const int* in_sizes, int n_in,
                              void* d_out, int out_size, void* d_ws, size_t ws_size,
                              hipStream_t stream) {
    const float* x      = (const float*)d_in[0];
    const int*   ei     = (const int*)d_in[1];
    const int*   etypes = (const int*)d_in[2];
    const int*   ntypes = (const int*)d_in[3];
    const float* W      = (const float*)d_in[4];
    float* out = (float*)d_out;

    int N = in_sizes[0] / C;    // 100000
    int E = in_sizes[2];        // 1600000

    half_t* sp = (half_t*)d_ws;
    half_t* dp = sp + (size_t)N * PPAD;

    int nblocks = (N + 255) / 256;
    node_proj_kernel<<<nblocks, 256, 0, stream>>>(x, ntypes, W, sp, dp, N);

    long total = (long)E * ODIM;
    int eblocks = (int)((total + 255) / 256);
    edge_kernel<<<eblocks, 256, 0, stream>>>(ei, etypes, sp, dp, W, out, E);
}